// Round 9
// baseline (347.686 us; speedup 1.0000x reference)
//
#include <hip/hip_runtime.h>
#include <hip/hip_fp16.h>

// DCell forward, MI355X (gfx950). All inputs/outputs fp32.
// R9: transpose rebuilt for LINEAR reads. Tile = 8 b-rows x 64 terms:
// each block reads 8 x 16KB contiguous gene runs (4KB dense per block-wide
// load step), packs fp32 {0,1} -> u8 in LDS, writes gT u8 [t][b][64] in 512-B
// contiguous chunks per term. R8's scattered-1KB reads ran at 1.67 TB/s; this
// should stream near copy BW.
// Downstream unchanged from R8 (passed): MFMA 16x16x32 f16 gemms with u8 gene
// A-frags expanded via exact bit trick; BN block-local; bias cancels in BN.
// ws: [gT3 u8 | gT2 | gT1 | h3 fp16 | h2 fp16 | h1 fp32 | z0p].

#define DEV static __device__ __forceinline__

constexpr int B_  = 256, G_ = 64, D_ = 20;
constexpr int T3_ = 2048, T2_ = 512, T1_ = 128;
constexpr float EPS_ = 1e-5f;

typedef unsigned char u8;

constexpr size_t OFF_GT3 = 0;
constexpr size_t SZ_GT3 = (size_t)T3_ * B_ * G_;
constexpr size_t OFF_GT2 = OFF_GT3 + SZ_GT3;
constexpr size_t SZ_GT2 = (size_t)T2_ * B_ * G_;
constexpr size_t OFF_GT1 = OFF_GT2 + SZ_GT2;
constexpr size_t SZ_GT1 = (size_t)T1_ * B_ * G_;
constexpr size_t OFF_H3B = OFF_GT1 + SZ_GT1;
constexpr size_t SZ_H3 = (size_t)T3_ * B_ * D_ * 2;
constexpr size_t OFF_H2B = OFF_H3B + SZ_H3;
constexpr size_t SZ_H2 = (size_t)T2_ * B_ * D_ * 2;
constexpr size_t OFF_H1B = OFF_H2B + SZ_H2;
constexpr size_t SZ_H1 = (size_t)B_ * T1_ * D_ * 4;
constexpr size_t OFF_Z0B = OFF_H1B + SZ_H1;

typedef _Float16 half8_t __attribute__((ext_vector_type(8)));
typedef float f32x4 __attribute__((ext_vector_type(4)));

DEV half8_t as_h8(uint4 u) {
    union { uint4 u4; half8_t h; } c; c.u4 = u; return c.h;
}

// 8 gene bytes (each 0/1) -> half8 {0.0h, 1.0h}. Exact: no carries possible.
DEV half8_t u8x8_to_h8(uint2 v) {
    uint4 r;
    uint x = v.x;
    r.x = ((x & 0xFFu) | ((x & 0xFF00u) << 8)) * 0x3C00u;
    r.y = (((x >> 16) & 0xFFu) | ((x >> 8) & 0xFF0000u)) * 0x3C00u;
    x = v.y;
    r.z = ((x & 0xFFu) | ((x & 0xFF00u) << 8)) * 0x3C00u;
    r.w = (((x >> 16) & 0xFFu) | ((x >> 8) & 0xFF0000u)) * 0x3C00u;
    return as_h8(r);
}

DEV float fast_tanh(float x) {
    float e = __expf(2.0f * x);
    return fmaf(-2.0f, __builtin_amdgcn_rcpf(e + 1.0f), 1.0f);
}

// ---- linear-read transpose: genes fp32 [256][T][64] -> gT u8 [t][b][64] -----
// Tile: 8 b x 64 t. Per block: 8 contiguous 16-KB reads; LDS u8 repack;
// 64 x 512-B contiguous writes. LDS rows padded (+4 uints) to spread banks.
constexpr int TRB = 8;      // batch rows per tile
constexpr int TRT = 64;     // terms per tile
constexpr int LROW = TRT * G_ / 4 + 4;   // 1028 uints per LDS row

__global__ __launch_bounds__(256, 4) void k_transpose_all(
        const float* __restrict__ g3s, const float* __restrict__ g2s,
        const float* __restrict__ g1s,
        u8* __restrict__ d3, u8* __restrict__ d2, u8* __restrict__ d1) {
    __shared__ uint lds[TRB * LROW];           // 32.9 KB
    int blk = blockIdx.x;
    const float* src; u8* dst; int T;
    constexpr int NB3 = (T3_ / TRT) * (B_ / TRB);   // 1024
    constexpr int NB2 = (T2_ / TRT) * (B_ / TRB);   // 256
    if (blk < NB3)              { src = g3s; dst = d3; T = T3_; }
    else if (blk < NB3 + NB2)   { blk -= NB3; src = g2s; dst = d2; T = T2_; }
    else                        { blk -= NB3 + NB2; src = g1s; dst = d1; T = T1_; }
    const int b0 = (blk & 31) * TRB;           // 32 b-tiles
    const int t0 = (blk >> 5) * TRT;
    const int tid = threadIdx.x;

    // read: 8 rows x 4096 floats (16 KB contiguous each)
#pragma unroll
    for (int it = 0; it < 32; ++it) {
        const int j = it * 256 + tid;          // 8192 float4s
        const int r = j >> 10, off = j & 1023; // off: float4 index within row
        float4 f = ((const float4*)(src + ((size_t)(b0 + r) * T + t0) * G_))[off];
        uint p = (uint)(u8)f.x | ((uint)(u8)f.y << 8) |
                 ((uint)(u8)f.z << 16) | ((uint)(u8)f.w << 24);
        lds[r * LROW + off] = p;               // bank = off%32: conflict-free
    }
    __syncthreads();

    // write: per t_local, 8 rows x 64 B = 512 B contiguous
#pragma unroll
    for (int it = 0; it < 8; ++it) {
        const int j = it * 256 + tid;          // 2048 uint4s
        const int t = j >> 5, r = (j >> 2) & 7, c = j & 3;
        const uint* row = lds + r * LROW + t * 16 + c * 4;   // 16B aligned
        uint4 v = make_uint4(row[0], row[1], row[2], row[3]);
        ((uint4*)(dst + (((size_t)(t0 + t) * B_) + b0 + r) * G_))[c] = v;
    }
}

// ---- MFMA GEMM + BN + tanh for strata 3/2/1 ---------------------------------
// NCHILD children (term-major fp16 [child][b][20]) + 64 genes (gT u8 [t][b][64]).
template <int T, int NCHILD, bool OUT_HALF>
__global__ __launch_bounds__(256, 4) void k_gemm(const __half* __restrict__ hsrc,
                                                 const u8* __restrict__ gT,
                                                 const float* __restrict__ W,
                                                 const float* __restrict__ g,
                                                 const float* __restrict__ be,
                                                 void* __restrict__ hout_) {
    constexpr int K_IN = NCHILD * 20 + 64;
    constexpr int NK = NCHILD + 2;
    constexpr int STRB = NCHILD ? 200 : 72;          // WT row stride in halfs
    __shared__ __half WT[32 * STRB];
    __shared__ float gv[D_], bev[D_];
    __shared__ float sred[4][16], qred[4][16];

    const int t = blockIdx.x, tid = threadIdx.x;

    uint* WTu = (uint*)WT;
    for (int j = tid; j < 32 * STRB / 2; j += 256) WTu[j] = 0;
    if (tid < D_) { gv[tid] = g[t * D_ + tid]; bev[tid] = be[t * D_ + tid]; }
    __syncthreads();
    const float* Wt = W + (size_t)t * (K_IN * D_);
    for (int j = tid; j < K_IN * D_; j += 256) {
        int k_orig = j / D_, o = j - k_orig * D_;
        int k_lds;
        if (NCHILD && k_orig < NCHILD * D_) {
            int c = k_orig / D_;
            k_lds = c * 32 + (k_orig - c * D_);
        } else {
            k_lds = NCHILD * 32 + (k_orig - NCHILD * D_);
        }
        WT[o * STRB + k_lds] = __float2half(Wt[j]);
    }
    __syncthreads();

    const int w = tid >> 6, lane = tid & 63;
    const int quad = lane >> 4, l15 = lane & 15;
    const int nt = w >> 1, mhalf = w & 1;
    const int ocol = nt * 16 + l15;                   // 0..31, valid < 20
    const int brow_base = mhalf * 128;                // 8 m-tiles of 16 rows

    half8_t Bf[NK];
#pragma unroll
    for (int ks = 0; ks < NK; ++ks)
        Bf[ks] = as_h8(*(const uint4*)(WT + ocol * STRB + ks * 32 + quad * 8));

    f32x4 acc[8];
#pragma unroll
    for (int mt = 0; mt < 8; ++mt) acc[mt] = (f32x4){0.f, 0.f, 0.f, 0.f};

#pragma unroll
    for (int mt = 0; mt < 8; ++mt) {
        const int bA = brow_base + mt * 16 + l15;     // A-operand row = lane&15
#pragma unroll
        for (int c = 0; c < NCHILD; ++c) {
            // h row is 20 halfs; quad*8 may run past 20 into the next row:
            // finite garbage x zero-padded WT => exact 0 contribution.
            const __half* ap = hsrc + ((size_t)(NCHILD * t + c) * B_ + bA) * D_ + quad * 8;
            uint2 u0 = *(const uint2*)(ap);
            uint2 u1 = *(const uint2*)(ap + 4);
            acc[mt] = __builtin_amdgcn_mfma_f32_16x16x32_f16(
                as_h8(make_uint4(u0.x, u0.y, u1.x, u1.y)), Bf[c], acc[mt], 0, 0, 0);
        }
        const u8* gp = gT + ((size_t)t * B_ + bA) * G_ + quad * 8;
#pragma unroll
        for (int ks = 0; ks < 2; ++ks) {
            uint2 au = *(const uint2*)(gp + ks * 32);
            acc[mt] = __builtin_amdgcn_mfma_f32_16x16x32_f16(
                u8x8_to_h8(au), Bf[NCHILD + ks], acc[mt], 0, 0, 0);
        }
    }

    // BN stats over batch: C/D layout row = quad*4+r, col = l15.
    float s = 0.f, q = 0.f;
#pragma unroll
    for (int mt = 0; mt < 8; ++mt)
#pragma unroll
        for (int r = 0; r < 4; ++r) {
            float z = acc[mt][r];
            s += z; q += z * z;
        }
    s += __shfl_xor(s, 16, 64); q += __shfl_xor(q, 16, 64);
    s += __shfl_xor(s, 32, 64); q += __shfl_xor(q, 32, 64);
    if (lane < 16) { sred[w][lane] = s; qred[w][lane] = q; }
    __syncthreads();
    const float S = sred[2 * nt][l15] + sred[2 * nt + 1][l15];
    const float Q = qred[2 * nt][l15] + qred[2 * nt + 1][l15];
    const float mu  = S * (1.0f / B_);
    const float var = fmaxf(Q * (1.0f / B_) - mu * mu, 0.0f);
    const float rstd = rsqrtf(var + EPS_);
    const int oc = ocol < D_ ? ocol : D_ - 1;
    const float A = rstd * gv[oc];
    const float C = bev[oc] - mu * A;

    if (ocol < D_) {
#pragma unroll
        for (int mt = 0; mt < 8; ++mt)
#pragma unroll
            for (int r = 0; r < 4; ++r) {
                float h = fast_tanh(fmaf(A, acc[mt][r], C));
                int b = brow_base + mt * 16 + quad * 4 + r;
                if (OUT_HALF) {
                    ((__half*)hout_)[((size_t)t * B_ + b) * D_ + ocol] = __float2half(h);
                } else {
                    ((float*)hout_)[((size_t)b * T + t) * D_ + ocol] = h;
                }
            }
    }
}

// ---- root GEMV, K-split x4 --------------------------------------------------
__global__ __launch_bounds__(256, 4) void k_stage0a(const float* __restrict__ h1,
                                                    const float* __restrict__ genes0,
                                                    const float* __restrict__ W0,
                                                    float* __restrict__ z0p) {
    const int b = blockIdx.x >> 2, s = blockIdx.x & 3, tid = threadIdx.x;
    const int kbase = 640 * s;
    const float* x = h1 + (size_t)b * (T1_ * D_);
    float acc[D_] = {};
#pragma unroll
    for (int j = 0; j < 3; ++j) {
        int kl = tid + 256 * j;
        if (kl < 640) {
            int k = kbase + kl;
            float xk = x[k];
            const float4* w = (const float4*)(W0 + (size_t)k * D_);
#pragma unroll
            for (int v = 0; v < D_ / 4; ++v) {
                float4 f = w[v];
                acc[4 * v + 0] = fmaf(xk, f.x, acc[4 * v + 0]);
                acc[4 * v + 1] = fmaf(xk, f.y, acc[4 * v + 1]);
                acc[4 * v + 2] = fmaf(xk, f.z, acc[4 * v + 2]);
                acc[4 * v + 3] = fmaf(xk, f.w, acc[4 * v + 3]);
            }
        }
    }
    if (s == 3 && tid < G_) {
        float xk = genes0[(size_t)b * G_ + tid];
        const float4* w = (const float4*)(W0 + (size_t)(T1_ * D_ + tid) * D_);
#pragma unroll
        for (int v = 0; v < D_ / 4; ++v) {
            float4 f = w[v];
            acc[4 * v + 0] = fmaf(xk, f.x, acc[4 * v + 0]);
            acc[4 * v + 1] = fmaf(xk, f.y, acc[4 * v + 1]);
            acc[4 * v + 2] = fmaf(xk, f.z, acc[4 * v + 2]);
            acc[4 * v + 3] = fmaf(xk, f.w, acc[4 * v + 3]);
        }
    }
    __shared__ float sred[4][D_];
    const int lane = tid & 63, wave = tid >> 6;
#pragma unroll
    for (int off = 32; off; off >>= 1)
#pragma unroll
        for (int o = 0; o < D_; ++o) acc[o] += __shfl_xor(acc[o], off, 64);
    if (lane == 0)
#pragma unroll
        for (int o = 0; o < D_; ++o) sred[wave][o] = acc[o];
    __syncthreads();
    if (tid < D_)
        z0p[((size_t)b * 4 + s) * D_ + tid] =
            sred[0][tid] + sred[1][tid] + sred[2][tid] + sred[3][tid];
}

// ---- root BN + tanh + head --------------------------------------------------
__global__ __launch_bounds__(256) void k_stage0b(const float* __restrict__ z0p,
                                                 const float* __restrict__ g0,
                                                 const float* __restrict__ be0,
                                                 const float* __restrict__ hw0,
                                                 const float* __restrict__ hb0,
                                                 float* __restrict__ out) {
    const int tid = threadIdx.x;   // == batch row
    float acc[D_] = {};
#pragma unroll
    for (int s = 0; s < 4; ++s) {
        const float4* zp = (const float4*)(z0p + ((size_t)tid * 4 + s) * D_);
#pragma unroll
        for (int v = 0; v < D_ / 4; ++v) {
            float4 f = zp[v];
            acc[4 * v + 0] += f.x; acc[4 * v + 1] += f.y;
            acc[4 * v + 2] += f.z; acc[4 * v + 3] += f.w;
        }
    }
    __shared__ float sred[4][D_], qred[4][D_], Avec[D_], Cvec[D_], hwv[D_ + 1];
    const int lane = tid & 63, wave = tid >> 6;
    float s[D_], q[D_];
#pragma unroll
    for (int o = 0; o < D_; ++o) { s[o] = acc[o]; q[o] = acc[o] * acc[o]; }
#pragma unroll
    for (int off = 32; off; off >>= 1) {
#pragma unroll
        for (int o = 0; o < D_; ++o) {
            s[o] += __shfl_xor(s[o], off, 64);
            q[o] += __shfl_xor(q[o], off, 64);
        }
    }
    if (lane == 0) {
#pragma unroll
        for (int o = 0; o < D_; ++o) { sred[wave][o] = s[o]; qred[wave][o] = q[o]; }
    }
    __syncthreads();
    if (tid < D_) {
        float S = sred[0][tid] + sred[1][tid] + sred[2][tid] + sred[3][tid];
        float Q = qred[0][tid] + qred[1][tid] + qred[2][tid] + qred[3][tid];
        float mu  = S * (1.0f / B_);
        float var = fmaxf(Q * (1.0f / B_) - mu * mu, 0.0f);
        float rstd = rsqrtf(var + EPS_);
        float A = rstd * g0[tid];
        Avec[tid] = A;
        Cvec[tid] = be0[tid] - mu * A;
        hwv[tid] = hw0[tid];
    }
    if (tid == 0) hwv[D_] = hb0[0];
    __syncthreads();
    float pred = hwv[D_];
#pragma unroll
    for (int o = 0; o < D_; ++o) {
        float h = fast_tanh(fmaf(acc[o], Avec[o], Cvec[o]));
        pred = fmaf(h, hwv[o], pred);
    }
    out[tid] = pred;
}

extern "C" void kernel_launch(void* const* d_in, const int* in_sizes, int n_in,
                              void* d_out, int out_size, void* d_ws, size_t ws_size,
                              hipStream_t stream) {
    const float* genes3 = (const float*)d_in[0];
    const float* genes2 = (const float*)d_in[1];
    const float* genes1 = (const float*)d_in[2];
    const float* genes0 = (const float*)d_in[3];
    const float* W3  = (const float*)d_in[4];
    const float* g3  = (const float*)d_in[6];
    const float* be3 = (const float*)d_in[7];
    const float* W2  = (const float*)d_in[8];
    const float* g2  = (const float*)d_in[10];
    const float* be2 = (const float*)d_in[11];
    const float* W1  = (const float*)d_in[12];
    const float* g1  = (const float*)d_in[14];
    const float* be1 = (const float*)d_in[15];
    const float* W0  = (const float*)d_in[16];
    const float* g0  = (const float*)d_in[18];
    const float* be0 = (const float*)d_in[19];
    const float* hw0 = (const float*)d_in[20];
    const float* hb0 = (const float*)d_in[21];

    char* wsb = (char*)d_ws;
    u8* gT3 = (u8*)(wsb + OFF_GT3);
    u8* gT2 = (u8*)(wsb + OFF_GT2);
    u8* gT1 = (u8*)(wsb + OFF_GT1);
    __half* h3  = (__half*)(wsb + OFF_H3B);
    __half* h2  = (__half*)(wsb + OFF_H2B);
    float*  h1  = (float*)(wsb + OFF_H1B);
    float*  z0p = (float*)(wsb + OFF_Z0B);

    constexpr int NTB = (T3_ / TRT + T2_ / TRT + T1_ / TRT) * (B_ / TRB);  // 1344
    k_transpose_all<<<NTB, 256, 0, stream>>>(genes3, genes2, genes1, gT3, gT2, gT1);
    k_gemm<T3_, 0, true ><<<T3_, 256, 0, stream>>>(nullptr, gT3, W3, g3, be3, h3);
    k_gemm<T2_, 4, true ><<<T2_, 256, 0, stream>>>(h3, gT2, W2, g2, be2, h2);
    k_gemm<T1_, 4, false><<<T1_, 256, 0, stream>>>(h2, gT1, W1, g1, be1, h1);
    k_stage0a<<<B_ * 4, 256, 0, stream>>>(h1, genes0, W0, z0p);
    k_stage0b<<<1, 256, 0, stream>>>(z0p, g0, be0, hw0, hb0, (float*)d_out);
}

// Round 10
// 324.715 us; speedup vs baseline: 1.0707x; 1.0707x over previous
//
#include <hip/hip_runtime.h>
#include <hip/hip_fp16.h>

// DCell forward, MI355X (gfx950). All inputs/outputs fp32.
// R10: genes are binary => transpose packs 64 genes -> one u64 bitmask per
// (t,b). gT shrinks 8x (gT3 4.2MB): transpose write-scatter becomes ~5.5MB
// total, gemm gene reads become one 8-B load per lane per m-tile. Transpose
// reads are perfectly dense (lane-contiguous float4, 4KB/wave-instr); nibble
// pack via padded LDS (conflict-free both phases). Gemms expand byte->half8
// with exact bit trick ((b0|b1<<16)*0x3C00: no carries).
// Downstream MFMA structure unchanged from R8/R9 (passed).
// ws: [gTb3 u64 | gTb2 | gTb1 | h3 fp16 | h2 fp16 | h1 fp32 | z0p] ~35 MB.

#define DEV static __device__ __forceinline__

constexpr int B_  = 256, G_ = 64, D_ = 20;
constexpr int T3_ = 2048, T2_ = 512, T1_ = 128;
constexpr float EPS_ = 1e-5f;

typedef unsigned char u8;
typedef unsigned long long u64;

constexpr size_t OFF_GTB3 = 0;
constexpr size_t SZ_GTB3 = (size_t)T3_ * B_ * 8;
constexpr size_t OFF_GTB2 = OFF_GTB3 + SZ_GTB3;
constexpr size_t SZ_GTB2 = (size_t)T2_ * B_ * 8;
constexpr size_t OFF_GTB1 = OFF_GTB2 + SZ_GTB2;
constexpr size_t SZ_GTB1 = (size_t)T1_ * B_ * 8;
constexpr size_t OFF_H3B = OFF_GTB1 + SZ_GTB1;
constexpr size_t SZ_H3 = (size_t)T3_ * B_ * D_ * 2;
constexpr size_t OFF_H2B = OFF_H3B + SZ_H3;
constexpr size_t SZ_H2 = (size_t)T2_ * B_ * D_ * 2;
constexpr size_t OFF_H1B = OFF_H2B + SZ_H2;
constexpr size_t SZ_H1 = (size_t)B_ * T1_ * D_ * 4;
constexpr size_t OFF_Z0B = OFF_H1B + SZ_H1;

typedef _Float16 half8_t __attribute__((ext_vector_type(8)));
typedef float f32x4 __attribute__((ext_vector_type(4)));

DEV half8_t as_h8(uint4 u) {
    union { uint4 u4; half8_t h; } c; c.u4 = u; return c.h;
}

// 8 gene BITS -> half8 {0.0h,1.0h}. Exact (no carries: operands are 0/1).
DEV half8_t bits8_to_h8(uint byte) {
    uint4 r;
    r.x = ((byte & 1u)        | ((byte & 2u)   << 15)) * 0x3C00u;
    r.y = (((byte >> 2) & 1u) | ((byte & 8u)   << 13)) * 0x3C00u;
    r.z = (((byte >> 4) & 1u) | ((byte & 32u)  << 11)) * 0x3C00u;
    r.w = (((byte >> 6) & 1u) | ((byte & 128u) << 9))  * 0x3C00u;
    return as_h8(r);
}

DEV float fast_tanh(float x) {
    float e = __expf(2.0f * x);
    return fmaf(-2.0f, __builtin_amdgcn_rcpf(e + 1.0f), 1.0f);
}

// ---- bit-pack transpose: genes fp32 [256][T][64] -> gTb u64 [t][b] ----------
// Block = (b, 128-term chunk): reads one 32-KB contiguous slab (dense
// lane-contiguous float4s), packs 4 predicate bits/thread into padded LDS
// nibbles, 128 threads assemble u64 rows, scattered 8-B writes (5.5 MB total).
__global__ __launch_bounds__(256, 8) void k_transpose_all(
        const float* __restrict__ g3s, const float* __restrict__ g2s,
        const float* __restrict__ g1s,
        u64* __restrict__ d3, u64* __restrict__ d2, u64* __restrict__ d1) {
    __shared__ uint nib[2048 + 128];           // padded: idx j -> j + (j>>4)
    int blk = blockIdx.x;
    const float* src; u64* dst; int T, b, tc;
    if (blk < 4096)      { src = g3s; dst = d3; T = T3_; b = blk >> 4; tc = blk & 15; }
    else if (blk < 5120) { blk -= 4096; src = g2s; dst = d2; T = T2_; b = blk >> 2; tc = blk & 3; }
    else                 { blk -= 5120; src = g1s; dst = d1; T = T1_; b = blk; tc = 0; }
    const int tid = threadIdx.x;
    const float4* base = (const float4*)(src + ((size_t)b * T + tc * 128) * G_);
#pragma unroll
    for (int it = 0; it < 8; ++it) {
        const int j = it * 256 + tid;          // float4 #j of the 32-KB slab
        float4 f = base[j];
        uint m = (f.x != 0.f ? 1u : 0u) | (f.y != 0.f ? 2u : 0u) |
                 (f.z != 0.f ? 4u : 0u) | (f.w != 0.f ? 8u : 0u);
        nib[j + (j >> 4)] = m;                 // row r=j/16, nibble i=j%16
    }
    __syncthreads();
    if (tid < 128) {                           // one u64 per term-row
        const uint* p = nib + 17 * tid;        // 17k mod 32: conflict-free
        uint lo = p[0]        | (p[1] << 4)  | (p[2] << 8)   | (p[3] << 12) |
                  (p[4] << 16) | (p[5] << 20) | (p[6] << 24) | (p[7] << 28);
        uint hi = p[8]        | (p[9] << 4)  | (p[10] << 8)  | (p[11] << 12) |
                  (p[12] << 16)| (p[13] << 20)| (p[14] << 24)| (p[15] << 28);
        dst[(size_t)(tc * 128 + tid) * B_ + b] = (u64)lo | ((u64)hi << 32);
    }
}

// ---- MFMA GEMM + BN + tanh for strata 3/2/1 ---------------------------------
// NCHILD children (term-major fp16 [child][b][20]) + 64 genes (gTb u64 [t][b]).
template <int T, int NCHILD, bool OUT_HALF>
__global__ __launch_bounds__(256, 4) void k_gemm(const __half* __restrict__ hsrc,
                                                 const u64* __restrict__ gTb,
                                                 const float* __restrict__ W,
                                                 const float* __restrict__ g,
                                                 const float* __restrict__ be,
                                                 void* __restrict__ hout_) {
    constexpr int K_IN = NCHILD * 20 + 64;
    constexpr int NK = NCHILD + 2;
    constexpr int STRB = NCHILD ? 200 : 72;          // WT row stride in halfs
    __shared__ __half WT[32 * STRB];
    __shared__ float gv[D_], bev[D_];
    __shared__ float sred[4][16], qred[4][16];

    const int t = blockIdx.x, tid = threadIdx.x;

    uint* WTu = (uint*)WT;
    for (int j = tid; j < 32 * STRB / 2; j += 256) WTu[j] = 0;
    if (tid < D_) { gv[tid] = g[t * D_ + tid]; bev[tid] = be[t * D_ + tid]; }
    __syncthreads();
    const float* Wt = W + (size_t)t * (K_IN * D_);
    for (int j = tid; j < K_IN * D_; j += 256) {
        int k_orig = j / D_, o = j - k_orig * D_;
        int k_lds;
        if (NCHILD && k_orig < NCHILD * D_) {
            int c = k_orig / D_;
            k_lds = c * 32 + (k_orig - c * D_);
        } else {
            k_lds = NCHILD * 32 + (k_orig - NCHILD * D_);
        }
        WT[o * STRB + k_lds] = __float2half(Wt[j]);
    }
    __syncthreads();

    const int w = tid >> 6, lane = tid & 63;
    const int quad = lane >> 4, l15 = lane & 15;
    const int nt = w >> 1, mhalf = w & 1;
    const int ocol = nt * 16 + l15;                   // 0..31, valid < 20
    const int brow_base = mhalf * 128;                // 8 m-tiles of 16 rows
    const int shq = quad * 8;

    half8_t Bf[NK];
#pragma unroll
    for (int ks = 0; ks < NK; ++ks)
        Bf[ks] = as_h8(*(const uint4*)(WT + ocol * STRB + ks * 32 + quad * 8));

    f32x4 acc[8];
#pragma unroll
    for (int mt = 0; mt < 8; ++mt) acc[mt] = (f32x4){0.f, 0.f, 0.f, 0.f};

#pragma unroll
    for (int mt = 0; mt < 8; ++mt) {
        const int bA = brow_base + mt * 16 + l15;     // A-operand row = lane&15
        const uint2 gu = ((const uint2*)gTb)[(size_t)t * B_ + bA];   // 64 gene bits
#pragma unroll
        for (int c = 0; c < NCHILD; ++c) {
            // h row is 20 halfs; quad*8 may run past 20 into the next row:
            // finite garbage x zero-padded WT => exact 0 contribution.
            const __half* ap = hsrc + ((size_t)(NCHILD * t + c) * B_ + bA) * D_ + quad * 8;
            uint2 u0 = *(const uint2*)(ap);
            uint2 u1 = *(const uint2*)(ap + 4);
            acc[mt] = __builtin_amdgcn_mfma_f32_16x16x32_f16(
                as_h8(make_uint4(u0.x, u0.y, u1.x, u1.y)), Bf[c], acc[mt], 0, 0, 0);
        }
        acc[mt] = __builtin_amdgcn_mfma_f32_16x16x32_f16(
            bits8_to_h8((gu.x >> shq) & 0xFFu), Bf[NCHILD], acc[mt], 0, 0, 0);
        acc[mt] = __builtin_amdgcn_mfma_f32_16x16x32_f16(
            bits8_to_h8((gu.y >> shq) & 0xFFu), Bf[NCHILD + 1], acc[mt], 0, 0, 0);
    }

    // BN stats over batch: C/D layout row = quad*4+r, col = l15.
    float s = 0.f, q = 0.f;
#pragma unroll
    for (int mt = 0; mt < 8; ++mt)
#pragma unroll
        for (int r = 0; r < 4; ++r) {
            float z = acc[mt][r];
            s += z; q += z * z;
        }
    s += __shfl_xor(s, 16, 64); q += __shfl_xor(q, 16, 64);
    s += __shfl_xor(s, 32, 64); q += __shfl_xor(q, 32, 64);
    if (lane < 16) { sred[w][lane] = s; qred[w][lane] = q; }
    __syncthreads();
    const float S = sred[2 * nt][l15] + sred[2 * nt + 1][l15];
    const float Q = qred[2 * nt][l15] + qred[2 * nt + 1][l15];
    const float mu  = S * (1.0f / B_);
    const float var = fmaxf(Q * (1.0f / B_) - mu * mu, 0.0f);
    const float rstd = rsqrtf(var + EPS_);
    const int oc = ocol < D_ ? ocol : D_ - 1;
    const float A = rstd * gv[oc];
    const float C = bev[oc] - mu * A;

    if (ocol < D_) {
#pragma unroll
        for (int mt = 0; mt < 8; ++mt)
#pragma unroll
            for (int r = 0; r < 4; ++r) {
                float h = fast_tanh(fmaf(A, acc[mt][r], C));
                int b = brow_base + mt * 16 + quad * 4 + r;
                if (OUT_HALF) {
                    ((__half*)hout_)[((size_t)t * B_ + b) * D_ + ocol] = __float2half(h);
                } else {
                    ((float*)hout_)[((size_t)b * T + t) * D_ + ocol] = h;
                }
            }
    }
}

// ---- root GEMV, K-split x4 --------------------------------------------------
__global__ __launch_bounds__(256, 4) void k_stage0a(const float* __restrict__ h1,
                                                    const float* __restrict__ genes0,
                                                    const float* __restrict__ W0,
                                                    float* __restrict__ z0p) {
    const int b = blockIdx.x >> 2, s = blockIdx.x & 3, tid = threadIdx.x;
    const int kbase = 640 * s;
    const float* x = h1 + (size_t)b * (T1_ * D_);
    float acc[D_] = {};
#pragma unroll
    for (int j = 0; j < 3; ++j) {
        int kl = tid + 256 * j;
        if (kl < 640) {
            int k = kbase + kl;
            float xk = x[k];
            const float4* w = (const float4*)(W0 + (size_t)k * D_);
#pragma unroll
            for (int v = 0; v < D_ / 4; ++v) {
                float4 f = w[v];
                acc[4 * v + 0] = fmaf(xk, f.x, acc[4 * v + 0]);
                acc[4 * v + 1] = fmaf(xk, f.y, acc[4 * v + 1]);
                acc[4 * v + 2] = fmaf(xk, f.z, acc[4 * v + 2]);
                acc[4 * v + 3] = fmaf(xk, f.w, acc[4 * v + 3]);
            }
        }
    }
    if (s == 3 && tid < G_) {
        float xk = genes0[(size_t)b * G_ + tid];
        const float4* w = (const float4*)(W0 + (size_t)(T1_ * D_ + tid) * D_);
#pragma unroll
        for (int v = 0; v < D_ / 4; ++v) {
            float4 f = w[v];
            acc[4 * v + 0] = fmaf(xk, f.x, acc[4 * v + 0]);
            acc[4 * v + 1] = fmaf(xk, f.y, acc[4 * v + 1]);
            acc[4 * v + 2] = fmaf(xk, f.z, acc[4 * v + 2]);
            acc[4 * v + 3] = fmaf(xk, f.w, acc[4 * v + 3]);
        }
    }
    __shared__ float sred[4][D_];
    const int lane = tid & 63, wave = tid >> 6;
#pragma unroll
    for (int off = 32; off; off >>= 1)
#pragma unroll
        for (int o = 0; o < D_; ++o) acc[o] += __shfl_xor(acc[o], off, 64);
    if (lane == 0)
#pragma unroll
        for (int o = 0; o < D_; ++o) sred[wave][o] = acc[o];
    __syncthreads();
    if (tid < D_)
        z0p[((size_t)b * 4 + s) * D_ + tid] =
            sred[0][tid] + sred[1][tid] + sred[2][tid] + sred[3][tid];
}

// ---- root BN + tanh + head --------------------------------------------------
__global__ __launch_bounds__(256) void k_stage0b(const float* __restrict__ z0p,
                                                 const float* __restrict__ g0,
                                                 const float* __restrict__ be0,
                                                 const float* __restrict__ hw0,
                                                 const float* __restrict__ hb0,
                                                 float* __restrict__ out) {
    const int tid = threadIdx.x;   // == batch row
    float acc[D_] = {};
#pragma unroll
    for (int s = 0; s < 4; ++s) {
        const float4* zp = (const float4*)(z0p + ((size_t)tid * 4 + s) * D_);
#pragma unroll
        for (int v = 0; v < D_ / 4; ++v) {
            float4 f = zp[v];
            acc[4 * v + 0] += f.x; acc[4 * v + 1] += f.y;
            acc[4 * v + 2] += f.z; acc[4 * v + 3] += f.w;
        }
    }
    __shared__ float sred[4][D_], qred[4][D_], Avec[D_], Cvec[D_], hwv[D_ + 1];
    const int lane = tid & 63, wave = tid >> 6;
    float s[D_], q[D_];
#pragma unroll
    for (int o = 0; o < D_; ++o) { s[o] = acc[o]; q[o] = acc[o] * acc[o]; }
#pragma unroll
    for (int off = 32; off; off >>= 1) {
#pragma unroll
        for (int o = 0; o < D_; ++o) {
            s[o] += __shfl_xor(s[o], off, 64);
            q[o] += __shfl_xor(q[o], off, 64);
        }
    }
    if (lane == 0) {
#pragma unroll
        for (int o = 0; o < D_; ++o) { sred[wave][o] = s[o]; qred[wave][o] = q[o]; }
    }
    __syncthreads();
    if (tid < D_) {
        float S = sred[0][tid] + sred[1][tid] + sred[2][tid] + sred[3][tid];
        float Q = qred[0][tid] + qred[1][tid] + qred[2][tid] + qred[3][tid];
        float mu  = S * (1.0f / B_);
        float var = fmaxf(Q * (1.0f / B_) - mu * mu, 0.0f);
        float rstd = rsqrtf(var + EPS_);
        float A = rstd * g0[tid];
        Avec[tid] = A;
        Cvec[tid] = be0[tid] - mu * A;
        hwv[tid] = hw0[tid];
    }
    if (tid == 0) hwv[D_] = hb0[0];
    __syncthreads();
    float pred = hwv[D_];
#pragma unroll
    for (int o = 0; o < D_; ++o) {
        float h = fast_tanh(fmaf(acc[o], Avec[o], Cvec[o]));
        pred = fmaf(h, hwv[o], pred);
    }
    out[tid] = pred;
}

extern "C" void kernel_launch(void* const* d_in, const int* in_sizes, int n_in,
                              void* d_out, int out_size, void* d_ws, size_t ws_size,
                              hipStream_t stream) {
    const float* genes3 = (const float*)d_in[0];
    const float* genes2 = (const float*)d_in[1];
    const float* genes1 = (const float*)d_in[2];
    const float* genes0 = (const float*)d_in[3];
    const float* W3  = (const float*)d_in[4];
    const float* g3  = (const float*)d_in[6];
    const float* be3 = (const float*)d_in[7];
    const float* W2  = (const float*)d_in[8];
    const float* g2  = (const float*)d_in[10];
    const float* be2 = (const float*)d_in[11];
    const float* W1  = (const float*)d_in[12];
    const float* g1  = (const float*)d_in[14];
    const float* be1 = (const float*)d_in[15];
    const float* W0  = (const float*)d_in[16];
    const float* g0  = (const float*)d_in[18];
    const float* be0 = (const float*)d_in[19];
    const float* hw0 = (const float*)d_in[20];
    const float* hb0 = (const float*)d_in[21];

    char* wsb = (char*)d_ws;
    u64* gTb3 = (u64*)(wsb + OFF_GTB3);
    u64* gTb2 = (u64*)(wsb + OFF_GTB2);
    u64* gTb1 = (u64*)(wsb + OFF_GTB1);
    __half* h3  = (__half*)(wsb + OFF_H3B);
    __half* h2  = (__half*)(wsb + OFF_H2B);
    float*  h1  = (float*)(wsb + OFF_H1B);
    float*  z0p = (float*)(wsb + OFF_Z0B);

    k_transpose_all<<<4096 + 1024 + 256, 256, 0, stream>>>(genes3, genes2, genes1,
                                                           gTb3, gTb2, gTb1);
    k_gemm<T3_, 0, true ><<<T3_, 256, 0, stream>>>(nullptr, gTb3, W3, g3, be3, h3);
    k_gemm<T2_, 4, true ><<<T2_, 256, 0, stream>>>(h3, gTb2, W2, g2, be2, h2);
    k_gemm<T1_, 4, false><<<T1_, 256, 0, stream>>>(h2, gTb1, W1, g1, be1, h1);
    k_stage0a<<<B_ * 4, 256, 0, stream>>>(h1, genes0, W0, z0p);
    k_stage0b<<<1, 256, 0, stream>>>(z0p, g0, be0, hw0, hb0, (float*)d_out);
}

// Round 11
// 324.237 us; speedup vs baseline: 1.0723x; 1.0015x over previous
//
#include <hip/hip_runtime.h>
#include <hip/hip_fp16.h>

// DCell forward, MI355X (gfx950). All inputs/outputs fp32.
// R11: gene bit-pack via WAVE BALLOT — lane l reads gene l of a row (dense
// 256B/wave-instr), __ballot(x!=0) IS the u64 bitmask (bit l = gene l, the
// exact layout gemm consumes). 8 rows/wave => 8 independent 4B loads/thread
// (32B MLP), no LDS, no syncs. Replaces R10's tiled transpose (~60-70us).
// Downstream unchanged from R10 (passed): MFMA 16x16x32 f16 gemms, u64 gene
// A-frags expanded via exact bit trick; BN block-local; bias cancels in BN.
// ws: [gTb3 u64 | gTb2 | gTb1 | h3 fp16 | h2 fp16 | h1 fp32 | z0p] ~35 MB.

#define DEV static __device__ __forceinline__

constexpr int B_  = 256, G_ = 64, D_ = 20;
constexpr int T3_ = 2048, T2_ = 512, T1_ = 128;
constexpr float EPS_ = 1e-5f;

typedef unsigned char u8;
typedef unsigned long long u64;

constexpr size_t OFF_GTB3 = 0;
constexpr size_t SZ_GTB3 = (size_t)T3_ * B_ * 8;
constexpr size_t OFF_GTB2 = OFF_GTB3 + SZ_GTB3;
constexpr size_t SZ_GTB2 = (size_t)T2_ * B_ * 8;
constexpr size_t OFF_GTB1 = OFF_GTB2 + SZ_GTB2;
constexpr size_t SZ_GTB1 = (size_t)T1_ * B_ * 8;
constexpr size_t OFF_H3B = OFF_GTB1 + SZ_GTB1;
constexpr size_t SZ_H3 = (size_t)T3_ * B_ * D_ * 2;
constexpr size_t OFF_H2B = OFF_H3B + SZ_H3;
constexpr size_t SZ_H2 = (size_t)T2_ * B_ * D_ * 2;
constexpr size_t OFF_H1B = OFF_H2B + SZ_H2;
constexpr size_t SZ_H1 = (size_t)B_ * T1_ * D_ * 4;
constexpr size_t OFF_Z0B = OFF_H1B + SZ_H1;

typedef _Float16 half8_t __attribute__((ext_vector_type(8)));
typedef float f32x4 __attribute__((ext_vector_type(4)));

DEV half8_t as_h8(uint4 u) {
    union { uint4 u4; half8_t h; } c; c.u4 = u; return c.h;
}

// 8 gene BITS -> half8 {0.0h,1.0h}. Exact (no carries: operands are 0/1).
DEV half8_t bits8_to_h8(uint byte) {
    uint4 r;
    r.x = ((byte & 1u)        | ((byte & 2u)   << 15)) * 0x3C00u;
    r.y = (((byte >> 2) & 1u) | ((byte & 8u)   << 13)) * 0x3C00u;
    r.z = (((byte >> 4) & 1u) | ((byte & 32u)  << 11)) * 0x3C00u;
    r.w = (((byte >> 6) & 1u) | ((byte & 128u) << 9))  * 0x3C00u;
    return as_h8(r);
}

DEV float fast_tanh(float x) {
    float e = __expf(2.0f * x);
    return fmaf(-2.0f, __builtin_amdgcn_rcpf(e + 1.0f), 1.0f);
}

// ---- ballot bit-pack: genes fp32 [256][T][64] -> gTb u64 [t][b] -------------
// Wave handles 8 consecutive rows (R = b*T + t). Lane l reads gene l of each
// row (dense 256B per wave-instruction, 8 loads in flight), __ballot gives the
// u64 mask directly (bit l = gene l). Lanes 0..7 store the 8 masks (t-major).
// Row counts per stratum (524288/131072/32768) are all divisible by 32, so a
// block (4 waves x 8 rows) never straddles strata.
__global__ __launch_bounds__(256, 8) void k_pack_all(
        const float* __restrict__ g3s, const float* __restrict__ g2s,
        const float* __restrict__ g1s,
        u64* __restrict__ d3, u64* __restrict__ d2, u64* __restrict__ d1) {
    constexpr int R3 = B_ * T3_;          // 524288
    constexpr int R2 = B_ * T2_;          // 131072
    const int lane = threadIdx.x & 63;
    int R0 = (blockIdx.x * 4 + (threadIdx.x >> 6)) * 8;
    const float* src; u64* dst; int shift;
    if (R0 < R3)            { src = g3s; dst = d3; shift = 11; }
    else if (R0 < R3 + R2)  { R0 -= R3; src = g2s; dst = d2; shift = 9; }
    else                    { R0 -= R3 + R2; src = g1s; dst = d1; shift = 7; }

    const float* p = src + (size_t)R0 * G_ + lane;
    float x[8];
#pragma unroll
    for (int r = 0; r < 8; ++r) x[r] = p[r * G_];
    u64 m[8];
#pragma unroll
    for (int r = 0; r < 8; ++r) m[r] = __ballot(x[r] != 0.0f);

    if (lane < 8) {
        u64 v = m[0];
        v = lane == 1 ? m[1] : v;
        v = lane == 2 ? m[2] : v;
        v = lane == 3 ? m[3] : v;
        v = lane == 4 ? m[4] : v;
        v = lane == 5 ? m[5] : v;
        v = lane == 6 ? m[6] : v;
        v = lane == 7 ? m[7] : v;
        const int R = R0 + lane;
        const int b = R >> shift, t = R - (b << shift);
        dst[(size_t)t * B_ + b] = v;
    }
}

// ---- MFMA GEMM + BN + tanh for strata 3/2/1 ---------------------------------
// NCHILD children (term-major fp16 [child][b][20]) + 64 genes (gTb u64 [t][b]).
template <int T, int NCHILD, bool OUT_HALF>
__global__ __launch_bounds__(256, 4) void k_gemm(const __half* __restrict__ hsrc,
                                                 const u64* __restrict__ gTb,
                                                 const float* __restrict__ W,
                                                 const float* __restrict__ g,
                                                 const float* __restrict__ be,
                                                 void* __restrict__ hout_) {
    constexpr int K_IN = NCHILD * 20 + 64;
    constexpr int NK = NCHILD + 2;
    constexpr int STRB = NCHILD ? 200 : 72;          // WT row stride in halfs
    __shared__ __half WT[32 * STRB];
    __shared__ float gv[D_], bev[D_];
    __shared__ float sred[4][16], qred[4][16];

    const int t = blockIdx.x, tid = threadIdx.x;

    uint* WTu = (uint*)WT;
    for (int j = tid; j < 32 * STRB / 2; j += 256) WTu[j] = 0;
    if (tid < D_) { gv[tid] = g[t * D_ + tid]; bev[tid] = be[t * D_ + tid]; }
    __syncthreads();
    const float* Wt = W + (size_t)t * (K_IN * D_);
    for (int j = tid; j < K_IN * D_; j += 256) {
        int k_orig = j / D_, o = j - k_orig * D_;
        int k_lds;
        if (NCHILD && k_orig < NCHILD * D_) {
            int c = k_orig / D_;
            k_lds = c * 32 + (k_orig - c * D_);
        } else {
            k_lds = NCHILD * 32 + (k_orig - NCHILD * D_);
        }
        WT[o * STRB + k_lds] = __float2half(Wt[j]);
    }
    __syncthreads();

    const int w = tid >> 6, lane = tid & 63;
    const int quad = lane >> 4, l15 = lane & 15;
    const int nt = w >> 1, mhalf = w & 1;
    const int ocol = nt * 16 + l15;                   // 0..31, valid < 20
    const int brow_base = mhalf * 128;                // 8 m-tiles of 16 rows
    const int shq = quad * 8;

    half8_t Bf[NK];
#pragma unroll
    for (int ks = 0; ks < NK; ++ks)
        Bf[ks] = as_h8(*(const uint4*)(WT + ocol * STRB + ks * 32 + quad * 8));

    f32x4 acc[8];
#pragma unroll
    for (int mt = 0; mt < 8; ++mt) acc[mt] = (f32x4){0.f, 0.f, 0.f, 0.f};

#pragma unroll
    for (int mt = 0; mt < 8; ++mt) {
        const int bA = brow_base + mt * 16 + l15;     // A-operand row = lane&15
        const uint2 gu = ((const uint2*)gTb)[(size_t)t * B_ + bA];   // 64 gene bits
#pragma unroll
        for (int c = 0; c < NCHILD; ++c) {
            // h row is 20 halfs; quad*8 may run past 20 into the next row:
            // finite garbage x zero-padded WT => exact 0 contribution.
            const __half* ap = hsrc + ((size_t)(NCHILD * t + c) * B_ + bA) * D_ + quad * 8;
            uint2 u0 = *(const uint2*)(ap);
            uint2 u1 = *(const uint2*)(ap + 4);
            acc[mt] = __builtin_amdgcn_mfma_f32_16x16x32_f16(
                as_h8(make_uint4(u0.x, u0.y, u1.x, u1.y)), Bf[c], acc[mt], 0, 0, 0);
        }
        acc[mt] = __builtin_amdgcn_mfma_f32_16x16x32_f16(
            bits8_to_h8((gu.x >> shq) & 0xFFu), Bf[NCHILD], acc[mt], 0, 0, 0);
        acc[mt] = __builtin_amdgcn_mfma_f32_16x16x32_f16(
            bits8_to_h8((gu.y >> shq) & 0xFFu), Bf[NCHILD + 1], acc[mt], 0, 0, 0);
    }

    // BN stats over batch: C/D layout row = quad*4+r, col = l15.
    float s = 0.f, q = 0.f;
#pragma unroll
    for (int mt = 0; mt < 8; ++mt)
#pragma unroll
        for (int r = 0; r < 4; ++r) {
            float z = acc[mt][r];
            s += z; q += z * z;
        }
    s += __shfl_xor(s, 16, 64); q += __shfl_xor(q, 16, 64);
    s += __shfl_xor(s, 32, 64); q += __shfl_xor(q, 32, 64);
    if (lane < 16) { sred[w][lane] = s; qred[w][lane] = q; }
    __syncthreads();
    const float S = sred[2 * nt][l15] + sred[2 * nt + 1][l15];
    const float Q = qred[2 * nt][l15] + qred[2 * nt + 1][l15];
    const float mu  = S * (1.0f / B_);
    const float var = fmaxf(Q * (1.0f / B_) - mu * mu, 0.0f);
    const float rstd = rsqrtf(var + EPS_);
    const int oc = ocol < D_ ? ocol : D_ - 1;
    const float A = rstd * gv[oc];
    const float C = bev[oc] - mu * A;

    if (ocol < D_) {
#pragma unroll
        for (int mt = 0; mt < 8; ++mt)
#pragma unroll
            for (int r = 0; r < 4; ++r) {
                float h = fast_tanh(fmaf(A, acc[mt][r], C));
                int b = brow_base + mt * 16 + quad * 4 + r;
                if (OUT_HALF) {
                    ((__half*)hout_)[((size_t)t * B_ + b) * D_ + ocol] = __float2half(h);
                } else {
                    ((float*)hout_)[((size_t)b * T + t) * D_ + ocol] = h;
                }
            }
    }
}

// ---- root GEMV, K-split x4 --------------------------------------------------
__global__ __launch_bounds__(256, 4) void k_stage0a(const float* __restrict__ h1,
                                                    const float* __restrict__ genes0,
                                                    const float* __restrict__ W0,
                                                    float* __restrict__ z0p) {
    const int b = blockIdx.x >> 2, s = blockIdx.x & 3, tid = threadIdx.x;
    const int kbase = 640 * s;
    const float* x = h1 + (size_t)b * (T1_ * D_);
    float acc[D_] = {};
#pragma unroll
    for (int j = 0; j < 3; ++j) {
        int kl = tid + 256 * j;
        if (kl < 640) {
            int k = kbase + kl;
            float xk = x[k];
            const float4* w = (const float4*)(W0 + (size_t)k * D_);
#pragma unroll
            for (int v = 0; v < D_ / 4; ++v) {
                float4 f = w[v];
                acc[4 * v + 0] = fmaf(xk, f.x, acc[4 * v + 0]);
                acc[4 * v + 1] = fmaf(xk, f.y, acc[4 * v + 1]);
                acc[4 * v + 2] = fmaf(xk, f.z, acc[4 * v + 2]);
                acc[4 * v + 3] = fmaf(xk, f.w, acc[4 * v + 3]);
            }
        }
    }
    if (s == 3 && tid < G_) {
        float xk = genes0[(size_t)b * G_ + tid];
        const float4* w = (const float4*)(W0 + (size_t)(T1_ * D_ + tid) * D_);
#pragma unroll
        for (int v = 0; v < D_ / 4; ++v) {
            float4 f = w[v];
            acc[4 * v + 0] = fmaf(xk, f.x, acc[4 * v + 0]);
            acc[4 * v + 1] = fmaf(xk, f.y, acc[4 * v + 1]);
            acc[4 * v + 2] = fmaf(xk, f.z, acc[4 * v + 2]);
            acc[4 * v + 3] = fmaf(xk, f.w, acc[4 * v + 3]);
        }
    }
    __shared__ float sred[4][D_];
    const int lane = tid & 63, wave = tid >> 6;
#pragma unroll
    for (int off = 32; off; off >>= 1)
#pragma unroll
        for (int o = 0; o < D_; ++o) acc[o] += __shfl_xor(acc[o], off, 64);
    if (lane == 0)
#pragma unroll
        for (int o = 0; o < D_; ++o) sred[wave][o] = acc[o];
    __syncthreads();
    if (tid < D_)
        z0p[((size_t)b * 4 + s) * D_ + tid] =
            sred[0][tid] + sred[1][tid] + sred[2][tid] + sred[3][tid];
}

// ---- root BN + tanh + head --------------------------------------------------
__global__ __launch_bounds__(256) void k_stage0b(const float* __restrict__ z0p,
                                                 const float* __restrict__ g0,
                                                 const float* __restrict__ be0,
                                                 const float* __restrict__ hw0,
                                                 const float* __restrict__ hb0,
                                                 float* __restrict__ out) {
    const int tid = threadIdx.x;   // == batch row
    float acc[D_] = {};
#pragma unroll
    for (int s = 0; s < 4; ++s) {
        const float4* zp = (const float4*)(z0p + ((size_t)tid * 4 + s) * D_);
#pragma unroll
        for (int v = 0; v < D_ / 4; ++v) {
            float4 f = zp[v];
            acc[4 * v + 0] += f.x; acc[4 * v + 1] += f.y;
            acc[4 * v + 2] += f.z; acc[4 * v + 3] += f.w;
        }
    }
    __shared__ float sred[4][D_], qred[4][D_], Avec[D_], Cvec[D_], hwv[D_ + 1];
    const int lane = tid & 63, wave = tid >> 6;
    float s[D_], q[D_];
#pragma unroll
    for (int o = 0; o < D_; ++o) { s[o] = acc[o]; q[o] = acc[o] * acc[o]; }
#pragma unroll
    for (int off = 32; off; off >>= 1) {
#pragma unroll
        for (int o = 0; o < D_; ++o) {
            s[o] += __shfl_xor(s[o], off, 64);
            q[o] += __shfl_xor(q[o], off, 64);
        }
    }
    if (lane == 0) {
#pragma unroll
        for (int o = 0; o < D_; ++o) { sred[wave][o] = s[o]; qred[wave][o] = q[o]; }
    }
    __syncthreads();
    if (tid < D_) {
        float S = sred[0][tid] + sred[1][tid] + sred[2][tid] + sred[3][tid];
        float Q = qred[0][tid] + qred[1][tid] + qred[2][tid] + qred[3][tid];
        float mu  = S * (1.0f / B_);
        float var = fmaxf(Q * (1.0f / B_) - mu * mu, 0.0f);
        float rstd = rsqrtf(var + EPS_);
        float A = rstd * g0[tid];
        Avec[tid] = A;
        Cvec[tid] = be0[tid] - mu * A;
        hwv[tid] = hw0[tid];
    }
    if (tid == 0) hwv[D_] = hb0[0];
    __syncthreads();
    float pred = hwv[D_];
#pragma unroll
    for (int o = 0; o < D_; ++o) {
        float h = fast_tanh(fmaf(acc[o], Avec[o], Cvec[o]));
        pred = fmaf(h, hwv[o], pred);
    }
    out[tid] = pred;
}

extern "C" void kernel_launch(void* const* d_in, const int* in_sizes, int n_in,
                              void* d_out, int out_size, void* d_ws, size_t ws_size,
                              hipStream_t stream) {
    const float* genes3 = (const float*)d_in[0];
    const float* genes2 = (const float*)d_in[1];
    const float* genes1 = (const float*)d_in[2];
    const float* genes0 = (const float*)d_in[3];
    const float* W3  = (const float*)d_in[4];
    const float* g3  = (const float*)d_in[6];
    const float* be3 = (const float*)d_in[7];
    const float* W2  = (const float*)d_in[8];
    const float* g2  = (const float*)d_in[10];
    const float* be2 = (const float*)d_in[11];
    const float* W1  = (const float*)d_in[12];
    const float* g1  = (const float*)d_in[14];
    const float* be1 = (const float*)d_in[15];
    const float* W0  = (const float*)d_in[16];
    const float* g0  = (const float*)d_in[18];
    const float* be0 = (const float*)d_in[19];
    const float* hw0 = (const float*)d_in[20];
    const float* hb0 = (const float*)d_in[21];

    char* wsb = (char*)d_ws;
    u64* gTb3 = (u64*)(wsb + OFF_GTB3);
    u64* gTb2 = (u64*)(wsb + OFF_GTB2);
    u64* gTb1 = (u64*)(wsb + OFF_GTB1);
    __half* h3  = (__half*)(wsb + OFF_H3B);
    __half* h2  = (__half*)(wsb + OFF_H2B);
    float*  h1  = (float*)(wsb + OFF_H1B);
    float*  z0p = (float*)(wsb + OFF_Z0B);

    // total rows = (2048+512+128)*256 = 688128; 32 rows per block
    k_pack_all<<<688128 / 32, 256, 0, stream>>>(genes3, genes2, genes1,
                                                gTb3, gTb2, gTb1);
    k_gemm<T3_, 0, true ><<<T3_, 256, 0, stream>>>(nullptr, gTb3, W3, g3, be3, h3);
    k_gemm<T2_, 4, true ><<<T2_, 256, 0, stream>>>(h3, gTb2, W2, g2, be2, h2);
    k_gemm<T1_, 4, false><<<T1_, 256, 0, stream>>>(h2, gTb1, W1, g1, be1, h1);
    k_stage0a<<<B_ * 4, 256, 0, stream>>>(h1, genes0, W0, z0p);
    k_stage0b<<<1, 256, 0, stream>>>(z0p, g0, be0, hw0, hb0, (float*)d_out);
}

// Round 12
// 322.464 us; speedup vs baseline: 1.0782x; 1.0055x over previous
//
#include <hip/hip_runtime.h>
#include <hip/hip_fp16.h>

// DCell forward, MI355X (gfx950). All inputs/outputs fp32.
// R12: (1) gemm epilogue via LDS transpose -> dense uint4 stores (was 32
// scattered 2B/4B stores per thread); (2) h1 now fp16 term-major, same
// epilogue, stage0a reads fp16; (3) gemm3 (K=64, no k-pad needed) skips the
// LDS zero + one barrier (garbage Bf for ocol>=20 lanes never contaminates
// valid outputs: per-lane acc -> per-ocol stats -> discarded at write).
// Carried: ballot bit-pack of genes (u64 mask = MFMA gene A-frag layout),
// MFMA 16x16x32 f16 per term, block-local BN, bias cancels in BN.
// ws: [gTb3 u64 | gTb2 | gTb1 | h3 fp16 | h2 fp16 | h1 fp16 | z0p] ~33 MB.

#define DEV static __device__ __forceinline__

constexpr int B_  = 256, G_ = 64, D_ = 20;
constexpr int T3_ = 2048, T2_ = 512, T1_ = 128;
constexpr float EPS_ = 1e-5f;

typedef unsigned char u8;
typedef unsigned long long u64;

constexpr size_t OFF_GTB3 = 0;
constexpr size_t SZ_GTB3 = (size_t)T3_ * B_ * 8;
constexpr size_t OFF_GTB2 = OFF_GTB3 + SZ_GTB3;
constexpr size_t SZ_GTB2 = (size_t)T2_ * B_ * 8;
constexpr size_t OFF_GTB1 = OFF_GTB2 + SZ_GTB2;
constexpr size_t SZ_GTB1 = (size_t)T1_ * B_ * 8;
constexpr size_t OFF_H3B = OFF_GTB1 + SZ_GTB1;
constexpr size_t SZ_H3 = (size_t)T3_ * B_ * D_ * 2;
constexpr size_t OFF_H2B = OFF_H3B + SZ_H3;
constexpr size_t SZ_H2 = (size_t)T2_ * B_ * D_ * 2;
constexpr size_t OFF_H1B = OFF_H2B + SZ_H2;
constexpr size_t SZ_H1 = (size_t)T1_ * B_ * D_ * 2;   // fp16 now
constexpr size_t OFF_Z0B = OFF_H1B + SZ_H1;

typedef _Float16 half8_t __attribute__((ext_vector_type(8)));
typedef float f32x4 __attribute__((ext_vector_type(4)));

DEV half8_t as_h8(uint4 u) {
    union { uint4 u4; half8_t h; } c; c.u4 = u; return c.h;
}

// 8 gene BITS -> half8 {0.0h,1.0h}. Exact (no carries: operands are 0/1).
DEV half8_t bits8_to_h8(uint byte) {
    uint4 r;
    r.x = ((byte & 1u)        | ((byte & 2u)   << 15)) * 0x3C00u;
    r.y = (((byte >> 2) & 1u) | ((byte & 8u)   << 13)) * 0x3C00u;
    r.z = (((byte >> 4) & 1u) | ((byte & 32u)  << 11)) * 0x3C00u;
    r.w = (((byte >> 6) & 1u) | ((byte & 128u) << 9))  * 0x3C00u;
    return as_h8(r);
}

DEV float fast_tanh(float x) {
    float e = __expf(2.0f * x);
    return fmaf(-2.0f, __builtin_amdgcn_rcpf(e + 1.0f), 1.0f);
}

// ---- ballot bit-pack: genes fp32 [256][T][64] -> gTb u64 [t][b] -------------
__global__ __launch_bounds__(256, 8) void k_pack_all(
        const float* __restrict__ g3s, const float* __restrict__ g2s,
        const float* __restrict__ g1s,
        u64* __restrict__ d3, u64* __restrict__ d2, u64* __restrict__ d1) {
    constexpr int R3 = B_ * T3_;          // 524288
    constexpr int R2 = B_ * T2_;          // 131072
    const int lane = threadIdx.x & 63;
    int R0 = (blockIdx.x * 4 + (threadIdx.x >> 6)) * 8;
    const float* src; u64* dst; int shift;
    if (R0 < R3)            { src = g3s; dst = d3; shift = 11; }
    else if (R0 < R3 + R2)  { R0 -= R3; src = g2s; dst = d2; shift = 9; }
    else                    { R0 -= R3 + R2; src = g1s; dst = d1; shift = 7; }

    const float* p = src + (size_t)R0 * G_ + lane;
    float x[8];
#pragma unroll
    for (int r = 0; r < 8; ++r) x[r] = p[r * G_];
    u64 m[8];
#pragma unroll
    for (int r = 0; r < 8; ++r) m[r] = __ballot(x[r] != 0.0f);

    if (lane < 8) {
        u64 v = m[0];
        v = lane == 1 ? m[1] : v;
        v = lane == 2 ? m[2] : v;
        v = lane == 3 ? m[3] : v;
        v = lane == 4 ? m[4] : v;
        v = lane == 5 ? m[5] : v;
        v = lane == 6 ? m[6] : v;
        v = lane == 7 ? m[7] : v;
        const int R = R0 + lane;
        const int b = R >> shift, t = R - (b << shift);
        dst[(size_t)t * B_ + b] = v;
    }
}

// ---- MFMA GEMM + BN + tanh for strata 3/2/1; fp16 term-major output ---------
template <int T, int NCHILD>
__global__ __launch_bounds__(256, 4) void k_gemm(const __half* __restrict__ hsrc,
                                                 const u64* __restrict__ gTb,
                                                 const float* __restrict__ W,
                                                 const float* __restrict__ g,
                                                 const float* __restrict__ be,
                                                 __half* __restrict__ hout) {
    constexpr int K_IN = NCHILD * 20 + 64;
    constexpr int NK = NCHILD + 2;
    constexpr int STRB = NCHILD ? 200 : 72;          // WT row stride in halfs
    constexpr int LDSH = (32 * STRB > B_ * D_) ? 32 * STRB : B_ * D_;
    __shared__ __align__(16) __half WT[LDSH];        // weights, then h-tile
    __shared__ float gv[D_], bev[D_];
    __shared__ float sred[4][16], qred[4][16];

    const int t = blockIdx.x, tid = threadIdx.x;

    if (NCHILD) {   // k-pad rows must be 0; gemm3 (K=64 exact) skips this
        uint* WTu = (uint*)WT;
        for (int j = tid; j < 32 * STRB / 2; j += 256) WTu[j] = 0;
        __syncthreads();
    }
    if (tid < D_) { gv[tid] = g[t * D_ + tid]; bev[tid] = be[t * D_ + tid]; }
    const float* Wt = W + (size_t)t * (K_IN * D_);
    for (int j = tid; j < K_IN * D_; j += 256) {
        int k_orig = j / D_, o = j - k_orig * D_;
        int k_lds;
        if (NCHILD && k_orig < NCHILD * D_) {
            int c = k_orig / D_;
            k_lds = c * 32 + (k_orig - c * D_);
        } else {
            k_lds = NCHILD * 32 + (k_orig - NCHILD * D_);
        }
        WT[o * STRB + k_lds] = __float2half(Wt[j]);
    }
    __syncthreads();

    const int w = tid >> 6, lane = tid & 63;
    const int quad = lane >> 4, l15 = lane & 15;
    const int nt = w >> 1, mhalf = w & 1;
    const int ocol = nt * 16 + l15;                   // 0..31, valid < 20
    const int brow_base = mhalf * 128;                // 8 m-tiles of 16 rows
    const int shq = quad * 8;

    half8_t Bf[NK];
#pragma unroll
    for (int ks = 0; ks < NK; ++ks)
        Bf[ks] = as_h8(*(const uint4*)(WT + ocol * STRB + ks * 32 + quad * 8));

    f32x4 acc[8];
#pragma unroll
    for (int mt = 0; mt < 8; ++mt) acc[mt] = (f32x4){0.f, 0.f, 0.f, 0.f};

#pragma unroll
    for (int mt = 0; mt < 8; ++mt) {
        const int bA = brow_base + mt * 16 + l15;     // A-operand row = lane&15
        const uint2 gu = ((const uint2*)gTb)[(size_t)t * B_ + bA];   // 64 gene bits
#pragma unroll
        for (int c = 0; c < NCHILD; ++c) {
            // h row is 20 halfs; quad*8 may run past 20 into the next row:
            // finite garbage x zero-padded WT => exact 0 contribution.
            const __half* ap = hsrc + ((size_t)(NCHILD * t + c) * B_ + bA) * D_ + quad * 8;
            uint2 u0 = *(const uint2*)(ap);
            uint2 u1 = *(const uint2*)(ap + 4);
            acc[mt] = __builtin_amdgcn_mfma_f32_16x16x32_f16(
                as_h8(make_uint4(u0.x, u0.y, u1.x, u1.y)), Bf[c], acc[mt], 0, 0, 0);
        }
        acc[mt] = __builtin_amdgcn_mfma_f32_16x16x32_f16(
            bits8_to_h8((gu.x >> shq) & 0xFFu), Bf[NCHILD], acc[mt], 0, 0, 0);
        acc[mt] = __builtin_amdgcn_mfma_f32_16x16x32_f16(
            bits8_to_h8((gu.y >> shq) & 0xFFu), Bf[NCHILD + 1], acc[mt], 0, 0, 0);
    }

    // BN stats over batch: C/D layout row = quad*4+r, col = l15.
    float s = 0.f, q = 0.f;
#pragma unroll
    for (int mt = 0; mt < 8; ++mt)
#pragma unroll
        for (int r = 0; r < 4; ++r) {
            float z = acc[mt][r];
            s += z; q += z * z;
        }
    s += __shfl_xor(s, 16, 64); q += __shfl_xor(q, 16, 64);
    s += __shfl_xor(s, 32, 64); q += __shfl_xor(q, 32, 64);
    if (lane < 16) { sred[w][lane] = s; qred[w][lane] = q; }
    __syncthreads();        // also: after this, no wave reads WT again (Bf in regs)
    const float S = sred[2 * nt][l15] + sred[2 * nt + 1][l15];
    const float Q = qred[2 * nt][l15] + qred[2 * nt + 1][l15];
    const float mu  = S * (1.0f / B_);
    const float var = fmaxf(Q * (1.0f / B_) - mu * mu, 0.0f);
    const float rstd = rsqrtf(var + EPS_);
    const int oc = ocol < D_ ? ocol : D_ - 1;
    const float A = rstd * gv[oc];
    const float C = bev[oc] - mu * A;

    // epilogue: LDS transpose (reuse WT) then dense uint4 stores (10 KB/term)
    if (ocol < D_) {
#pragma unroll
        for (int mt = 0; mt < 8; ++mt)
#pragma unroll
            for (int r = 0; r < 4; ++r) {
                float h = fast_tanh(fmaf(A, acc[mt][r], C));
                int b = brow_base + mt * 16 + quad * 4 + r;
                WT[b * D_ + ocol] = __float2half(h);
            }
    }
    __syncthreads();
    const uint4* src4 = (const uint4*)WT;
    uint4* dst4 = (uint4*)(hout + (size_t)t * (B_ * D_));
    for (int j = tid; j < (B_ * D_) / 8; j += 256) dst4[j] = src4[j];
}

// ---- root GEMV, K-split x4 (h1 fp16 term-major [t][b][20]) ------------------
__global__ __launch_bounds__(256, 4) void k_stage0a(const __half* __restrict__ h1,
                                                    const float* __restrict__ genes0,
                                                    const float* __restrict__ W0,
                                                    float* __restrict__ z0p) {
    const int b = blockIdx.x >> 2, s = blockIdx.x & 3, tid = threadIdx.x;
    const int kbase = 640 * s;
    float acc[D_] = {};
#pragma unroll
    for (int j = 0; j < 3; ++j) {
        int kl = tid + 256 * j;
        if (kl < 640) {
            int k = kbase + kl;
            int tt = k / D_, o = k - tt * D_;
            float xk = __half2float(h1[((size_t)tt * B_ + b) * D_ + o]);
            const float4* w = (const float4*)(W0 + (size_t)k * D_);
#pragma unroll
            for (int v = 0; v < D_ / 4; ++v) {
                float4 f = w[v];
                acc[4 * v + 0] = fmaf(xk, f.x, acc[4 * v + 0]);
                acc[4 * v + 1] = fmaf(xk, f.y, acc[4 * v + 1]);
                acc[4 * v + 2] = fmaf(xk, f.z, acc[4 * v + 2]);
                acc[4 * v + 3] = fmaf(xk, f.w, acc[4 * v + 3]);
            }
        }
    }
    if (s == 3 && tid < G_) {
        float xk = genes0[(size_t)b * G_ + tid];
        const float4* w = (const float4*)(W0 + (size_t)(T1_ * D_ + tid) * D_);
#pragma unroll
        for (int v = 0; v < D_ / 4; ++v) {
            float4 f = w[v];
            acc[4 * v + 0] = fmaf(xk, f.x, acc[4 * v + 0]);
            acc[4 * v + 1] = fmaf(xk, f.y, acc[4 * v + 1]);
            acc[4 * v + 2] = fmaf(xk, f.z, acc[4 * v + 2]);
            acc[4 * v + 3] = fmaf(xk, f.w, acc[4 * v + 3]);
        }
    }
    __shared__ float sred[4][D_];
    const int lane = tid & 63, wave = tid >> 6;
#pragma unroll
    for (int off = 32; off; off >>= 1)
#pragma unroll
        for (int o = 0; o < D_; ++o) acc[o] += __shfl_xor(acc[o], off, 64);
    if (lane == 0)
#pragma unroll
        for (int o = 0; o < D_; ++o) sred[wave][o] = acc[o];
    __syncthreads();
    if (tid < D_)
        z0p[((size_t)b * 4 + s) * D_ + tid] =
            sred[0][tid] + sred[1][tid] + sred[2][tid] + sred[3][tid];
}

// ---- root BN + tanh + head --------------------------------------------------
__global__ __launch_bounds__(256) void k_stage0b(const float* __restrict__ z0p,
                                                 const float* __restrict__ g0,
                                                 const float* __restrict__ be0,
                                                 const float* __restrict__ hw0,
                                                 const float* __restrict__ hb0,
                                                 float* __restrict__ out) {
    const int tid = threadIdx.x;   // == batch row
    float acc[D_] = {};
#pragma unroll
    for (int s = 0; s < 4; ++s) {
        const float4* zp = (const float4*)(z0p + ((size_t)tid * 4 + s) * D_);
#pragma unroll
        for (int v = 0; v < D_ / 4; ++v) {
            float4 f = zp[v];
            acc[4 * v + 0] += f.x; acc[4 * v + 1] += f.y;
            acc[4 * v + 2] += f.z; acc[4 * v + 3] += f.w;
        }
    }
    __shared__ float sred[4][D_], qred[4][D_], Avec[D_], Cvec[D_], hwv[D_ + 1];
    const int lane = tid & 63, wave = tid >> 6;
    float s[D_], q[D_];
#pragma unroll
    for (int o = 0; o < D_; ++o) { s[o] = acc[o]; q[o] = acc[o] * acc[o]; }
#pragma unroll
    for (int off = 32; off; off >>= 1) {
#pragma unroll
        for (int o = 0; o < D_; ++o) {
            s[o] += __shfl_xor(s[o], off, 64);
            q[o] += __shfl_xor(q[o], off, 64);
        }
    }
    if (lane == 0) {
#pragma unroll
        for (int o = 0; o < D_; ++o) { sred[wave][o] = s[o]; qred[wave][o] = q[o]; }
    }
    __syncthreads();
    if (tid < D_) {
        float S = sred[0][tid] + sred[1][tid] + sred[2][tid] + sred[3][tid];
        float Q = qred[0][tid] + qred[1][tid] + qred[2][tid] + qred[3][tid];
        float mu  = S * (1.0f / B_);
        float var = fmaxf(Q * (1.0f / B_) - mu * mu, 0.0f);
        float rstd = rsqrtf(var + EPS_);
        float A = rstd * g0[tid];
        Avec[tid] = A;
        Cvec[tid] = be0[tid] - mu * A;
        hwv[tid] = hw0[tid];
    }
    if (tid == 0) hwv[D_] = hb0[0];
    __syncthreads();
    float pred = hwv[D_];
#pragma unroll
    for (int o = 0; o < D_; ++o) {
        float h = fast_tanh(fmaf(acc[o], Avec[o], Cvec[o]));
        pred = fmaf(h, hwv[o], pred);
    }
    out[tid] = pred;
}

extern "C" void kernel_launch(void* const* d_in, const int* in_sizes, int n_in,
                              void* d_out, int out_size, void* d_ws, size_t ws_size,
                              hipStream_t stream) {
    const float* genes3 = (const float*)d_in[0];
    const float* genes2 = (const float*)d_in[1];
    const float* genes1 = (const float*)d_in[2];
    const float* genes0 = (const float*)d_in[3];
    const float* W3  = (const float*)d_in[4];
    const float* g3  = (const float*)d_in[6];
    const float* be3 = (const float*)d_in[7];
    const float* W2  = (const float*)d_in[8];
    const float* g2  = (const float*)d_in[10];
    const float* be2 = (const float*)d_in[11];
    const float* W1  = (const float*)d_in[12];
    const float* g1  = (const float*)d_in[14];
    const float* be1 = (const float*)d_in[15];
    const float* W0  = (const float*)d_in[16];
    const float* g0  = (const float*)d_in[18];
    const float* be0 = (const float*)d_in[19];
    const float* hw0 = (const float*)d_in[20];
    const float* hb0 = (const float*)d_in[21];

    char* wsb = (char*)d_ws;
    u64* gTb3 = (u64*)(wsb + OFF_GTB3);
    u64* gTb2 = (u64*)(wsb + OFF_GTB2);
    u64* gTb1 = (u64*)(wsb + OFF_GTB1);
    __half* h3  = (__half*)(wsb + OFF_H3B);
    __half* h2  = (__half*)(wsb + OFF_H2B);
    __half* h1  = (__half*)(wsb + OFF_H1B);
    float*  z0p = (float*)(wsb + OFF_Z0B);

    // total rows = (2048+512+128)*256 = 688128; 32 rows per block
    k_pack_all<<<688128 / 32, 256, 0, stream>>>(genes3, genes2, genes1,
                                                gTb3, gTb2, gTb1);
    k_gemm<T3_, 0><<<T3_, 256, 0, stream>>>(nullptr, gTb3, W3, g3, be3, h3);
    k_gemm<T2_, 4><<<T2_, 256, 0, stream>>>(h3, gTb2, W2, g2, be2, h2);
    k_gemm<T1_, 4><<<T1_, 256, 0, stream>>>(h2, gTb1, W1, g1, be1, h1);
    k_stage0a<<<B_ * 4, 256, 0, stream>>>(h1, genes0, W0, z0p);
    k_stage0b<<<1, 256, 0, stream>>>(z0p, g0, be0, hw0, hb0, (float*)d_out);
}